// Round 14
// baseline (149.146 us; speedup 1.0000x reference)
//
#include <hip/hip_runtime.h>
#include <hip/hip_bf16.h>

#define N_NODES 12000
#define N_EDGES 384000
#define F_IN 512
#define H 64
#define C_CLS 7
#define KTERMS 16
#define PAD 96
#define CSTR 32
#define NBLK 640
#define GEMM_BLKS 188
#define FILL_BLKS (NBLK - GEMM_BLKS)
#define MOM_BLKS 192
#define NB 4
#define XS_STR 68

__device__ __forceinline__ float wred_f(float x) {
    #pragma unroll
    for (int o = 32; o > 0; o >>= 1) x += __shfl_xor(x, o);
    return x;
}

// sc1 write-through store: data reaches L3 (agent coherence point).
__device__ __forceinline__ void stc(float* p, float v) {
    __hip_atomic_store(p, v, __ATOMIC_RELAXED, __HIP_MEMORY_SCOPE_AGENT);
}

// Striped tree barrier: 8 stripe counters (80 blocks each) -> root -> 8 release
// flags. Relaxed atomics only (no cache maintenance); constant s_sleep(8)
// backoff (~0.2us detection). bar zeroed by init_k each call; gens 1..4.
__device__ __forceinline__ void gsync(int* bar, int gen) {
    __syncthreads();
    if (threadIdx.x == 0) {
        const int s = blockIdx.x & 7;
        int pos = __hip_atomic_fetch_add(&bar[s * 32], 1, __ATOMIC_RELAXED,
                                         __HIP_MEMORY_SCOPE_AGENT);
        if (pos == 80 * gen - 1) {
            int r = __hip_atomic_fetch_add(&bar[320], 1, __ATOMIC_RELAXED,
                                           __HIP_MEMORY_SCOPE_AGENT);
            if (r == 8 * gen - 1) {
                #pragma unroll
                for (int k = 0; k < 8; ++k)
                    __hip_atomic_store(&bar[512 + k * 32], gen, __ATOMIC_RELAXED,
                                       __HIP_MEMORY_SCOPE_AGENT);
            }
        }
        while (__hip_atomic_load(&bar[512 + s * 32], __ATOMIC_RELAXED,
                                 __HIP_MEMORY_SCOPE_AGENT) < gen)
            __builtin_amdgcn_s_sleep(8);
        asm volatile("" ::: "memory");
    }
    __syncthreads();
}

// ---------------- k0: zero cur lines, M, m0, bar
__global__ __launch_bounds__(256) void init_k(int* __restrict__ cur,
                                              double* __restrict__ M,
                                              double* __restrict__ m0,
                                              int* __restrict__ bar) {
    int i = blockIdx.x * 256 + threadIdx.x;
    if (i < N_NODES) cur[i * CSTR] = 0;
    if (i < KTERMS * 64) M[i] = 0.0;
    if (i < KTERMS) m0[i] = 0.0;
    if (i < 768) bar[i] = 0;
}

// ---------------- mega kernel: all phases, 4 grid barriers
__global__ __launch_bounds__(256, 4) void mega_k(
        const float* __restrict__ x, const float* __restrict__ W1,
        const float* __restrict__ b1, const float* __restrict__ W2,
        const float* __restrict__ b2, const float* __restrict__ aux,
        const float* __restrict__ clfW, const float* __restrict__ clfb,
        const int* __restrict__ ei,
        float* __restrict__ hbuf, float* __restrict__ h1, float* __restrict__ h2,
        float* __restrict__ score, int* __restrict__ csrc, int* __restrict__ cur,
        double* __restrict__ M, double* __restrict__ m0, int* __restrict__ bar,
        float* __restrict__ out) {
    __shared__ __align__(16) char smem[33792];
    const int b = blockIdx.x, t = threadIdx.x;
    const int f = t & 63, w = t >> 6;

    // ===== phase A: gemm1 (blocks 0..187, 64-row tiles, 4x4 reg tiles) || fill =====
    if (b < GEMM_BLKS) {
        float* xs  = (float*)smem;             // [64][XS_STR]
        float* wsm = (float*)(smem + 17408);   // [64][64]
        const int tx = t & 15, ty = t >> 4;
        const int i0 = b * 64;
        float acc[4][4] = {};
        for (int k0 = 0; k0 < F_IN; k0 += 64) {
            #pragma unroll
            for (int q = 0; q < 4; ++q) {
                int idx = t + q * 256;
                int row = idx >> 4, kg = idx & 15;
                int rg = min(i0 + row, N_NODES - 1);
                *(float4*)(&xs[row * XS_STR + kg * 4]) =
                    *(const float4*)(x + (size_t)rg * F_IN + k0 + kg * 4);
            }
            #pragma unroll
            for (int q = 0; q < 4; ++q) {
                int idx = t + q * 256;
                int r = idx >> 4, cg = idx & 15;
                *(float4*)(&wsm[r * 64 + cg * 4]) =
                    *(const float4*)(W1 + (size_t)(k0 + r) * H + cg * 4);
            }
            __syncthreads();
            #pragma unroll
            for (int kk0 = 0; kk0 < 64; kk0 += 4) {
                float4 a0 = *(const float4*)(&xs[(ty * 4 + 0) * XS_STR + kk0]);
                float4 a1 = *(const float4*)(&xs[(ty * 4 + 1) * XS_STR + kk0]);
                float4 a2 = *(const float4*)(&xs[(ty * 4 + 2) * XS_STR + kk0]);
                float4 a3 = *(const float4*)(&xs[(ty * 4 + 3) * XS_STR + kk0]);
                float4 b0 = *(const float4*)(&wsm[(kk0 + 0) * 64 + tx * 4]);
                float4 b1v = *(const float4*)(&wsm[(kk0 + 1) * 64 + tx * 4]);
                float4 b2v = *(const float4*)(&wsm[(kk0 + 2) * 64 + tx * 4]);
                float4 b3v = *(const float4*)(&wsm[(kk0 + 3) * 64 + tx * 4]);
                acc[0][0] += a0.x * b0.x;  acc[0][1] += a0.x * b0.y;  acc[0][2] += a0.x * b0.z;  acc[0][3] += a0.x * b0.w;
                acc[0][0] += a0.y * b1v.x; acc[0][1] += a0.y * b1v.y; acc[0][2] += a0.y * b1v.z; acc[0][3] += a0.y * b1v.w;
                acc[0][0] += a0.z * b2v.x; acc[0][1] += a0.z * b2v.y; acc[0][2] += a0.z * b2v.z; acc[0][3] += a0.z * b2v.w;
                acc[0][0] += a0.w * b3v.x; acc[0][1] += a0.w * b3v.y; acc[0][2] += a0.w * b3v.z; acc[0][3] += a0.w * b3v.w;
                acc[1][0] += a1.x * b0.x;  acc[1][1] += a1.x * b0.y;  acc[1][2] += a1.x * b0.z;  acc[1][3] += a1.x * b0.w;
                acc[1][0] += a1.y * b1v.x; acc[1][1] += a1.y * b1v.y; acc[1][2] += a1.y * b1v.z; acc[1][3] += a1.y * b1v.w;
                acc[1][0] += a1.z * b2v.x; acc[1][1] += a1.z * b2v.y; acc[1][2] += a1.z * b2v.z; acc[1][3] += a1.z * b2v.w;
                acc[1][0] += a1.w * b3v.x; acc[1][1] += a1.w * b3v.y; acc[1][2] += a1.w * b3v.z; acc[1][3] += a1.w * b3v.w;
                acc[2][0] += a2.x * b0.x;  acc[2][1] += a2.x * b0.y;  acc[2][2] += a2.x * b0.z;  acc[2][3] += a2.x * b0.w;
                acc[2][0] += a2.y * b1v.x; acc[2][1] += a2.y * b1v.y; acc[2][2] += a2.y * b1v.z; acc[2][3] += a2.y * b1v.w;
                acc[2][0] += a2.z * b2v.x; acc[2][1] += a2.z * b2v.y; acc[2][2] += a2.z * b2v.z; acc[2][3] += a2.z * b2v.w;
                acc[2][0] += a2.w * b3v.x; acc[2][1] += a2.w * b3v.y; acc[2][2] += a2.w * b3v.z; acc[2][3] += a2.w * b3v.w;
                acc[3][0] += a3.x * b0.x;  acc[3][1] += a3.x * b0.y;  acc[3][2] += a3.x * b0.z;  acc[3][3] += a3.x * b0.w;
                acc[3][0] += a3.y * b1v.x; acc[3][1] += a3.y * b1v.y; acc[3][2] += a3.y * b1v.z; acc[3][3] += a3.y * b1v.w;
                acc[3][0] += a3.z * b2v.x; acc[3][1] += a3.z * b2v.y; acc[3][2] += a3.z * b2v.z; acc[3][3] += a3.z * b2v.w;
                acc[3][0] += a3.w * b3v.x; acc[3][1] += a3.w * b3v.y; acc[3][2] += a3.w * b3v.z; acc[3][3] += a3.w * b3v.w;
            }
            __syncthreads();
        }
        #pragma unroll
        for (int r = 0; r < 4; ++r) {
            int row = i0 + ty * 4 + r;
            if (row < N_NODES) {
                stc(&hbuf[(size_t)row * H + tx * 4 + 0], acc[r][0]);
                stc(&hbuf[(size_t)row * H + tx * 4 + 1], acc[r][1]);
                stc(&hbuf[(size_t)row * H + tx * 4 + 2], acc[r][2]);
                stc(&hbuf[(size_t)row * H + tx * 4 + 3], acc[r][3]);
            }
        }
    } else {
        for (int e = (b - GEMM_BLKS) * 256 + t; e < N_EDGES; e += FILL_BLKS * 256) {
            int s = ei[e];
            int d = ei[N_EDGES + e];
            int pos = __hip_atomic_fetch_add(&cur[d * CSTR], 1, __ATOMIC_RELAXED,
                                             __HIP_MEMORY_SCOPE_AGENT);
            if (pos < PAD)
                (void)__hip_atomic_exchange(&csrc[d * PAD + pos], s, __ATOMIC_RELAXED,
                                            __HIP_MEMORY_SCOPE_AGENT);
        }
    }
    gsync(bar, 1);

    // ===== phase B: agg1 = relu((A_hat @ hbuf) + b1), grid-stride groups =====
    {
        int2*  sPair = (int2*)smem;              // [NB*PAD] = 3072 B
        int*   sDeg  = (int*)(smem + 3072);
        float* sIsd  = (float*)(smem + 3088);
        for (int g = b; g < N_NODES / NB; g += NBLK) {
            const int base = g * NB;
            __syncthreads();
            if (t < NB) {
                int d = cur[(base + t) * CSTR];
                sDeg[t] = min(d, PAD);
                sIsd[t] = rsqrtf((float)d + 1.f);
            }
            __syncthreads();
            for (int idx = t; idx < NB * PAD; idx += 256) {
                int n = idx / PAD, e = idx - n * PAD;
                if (e < sDeg[n]) {
                    int s = csrc[(base + n) * PAD + e];
                    float ws_ = rsqrtf((float)cur[s * CSTR] + 1.f);
                    sPair[idx] = make_int2(s, __float_as_int(ws_));
                }
            }
            __syncthreads();
            const int i = base + w;
            const int deg = sDeg[w];
            const float isd = sIsd[w];
            const int2* pp = sPair + w * PAD;
            float acc = 0.f;
            int e = 0;
            for (; e + 4 <= deg; e += 4) {
                int2 p0 = pp[e], p1 = pp[e + 1], p2 = pp[e + 2], p3 = pp[e + 3];
                acc += hbuf[p0.x * H + f] * __int_as_float(p0.y)
                     + hbuf[p1.x * H + f] * __int_as_float(p1.y)
                     + hbuf[p2.x * H + f] * __int_as_float(p2.y)
                     + hbuf[p3.x * H + f] * __int_as_float(p3.y);
            }
            for (; e < deg; ++e) {
                int2 p = pp[e];
                acc += hbuf[p.x * H + f] * __int_as_float(p.y);
            }
            float res = (acc + hbuf[i * H + f] * isd) * isd + b1[f];
            stc(&h1[i * H + f], fmaxf(res, 0.f));
        }
    }
    gsync(bar, 2);

    // ===== phase C: agg2 = (A_hat @ h1) @ W2 + b2, + cosine score =====
    {
        int2*  sPair = (int2*)smem;              // 3072
        int*   sDeg  = (int*)(smem + 3072);
        float* sIsd  = (float*)(smem + 3088);
        float* w2s   = (float*)(smem + 3104);    // 16384
        float* anorm = (float*)(smem + 19488);   // 256
        float* gsh   = (float*)(smem + 19744);   // 1024
        #pragma unroll
        for (int q = 0; q < 4; ++q) {
            int idx = t + q * 256;
            int r = idx >> 4, c4 = idx & 15;
            *(float4*)(&w2s[r * 64 + c4 * 4]) = *(const float4*)(W2 + r * H + c4 * 4);
        }
        if (t < 64) {
            float av = aux[t];
            anorm[t] = av * rsqrtf(fmaxf(wred_f(av * av), 1e-24f));
        }
        for (int g = b; g < N_NODES / NB; g += NBLK) {
            const int base = g * NB;
            __syncthreads();
            if (t < NB) {
                int d = cur[(base + t) * CSTR];
                sDeg[t] = min(d, PAD);
                sIsd[t] = rsqrtf((float)d + 1.f);
            }
            __syncthreads();
            for (int idx = t; idx < NB * PAD; idx += 256) {
                int n = idx / PAD, e = idx - n * PAD;
                if (e < sDeg[n]) {
                    int s = csrc[(base + n) * PAD + e];
                    float ws_ = rsqrtf((float)cur[s * CSTR] + 1.f);
                    sPair[idx] = make_int2(s, __float_as_int(ws_));
                }
            }
            __syncthreads();
            const int i = base + w;
            const int deg = sDeg[w];
            const float isd = sIsd[w];
            const int2* pp = sPair + w * PAD;
            float acc = 0.f;
            int e = 0;
            for (; e + 4 <= deg; e += 4) {
                int2 p0 = pp[e], p1 = pp[e + 1], p2 = pp[e + 2], p3 = pp[e + 3];
                acc += h1[p0.x * H + f] * __int_as_float(p0.y)
                     + h1[p1.x * H + f] * __int_as_float(p1.y)
                     + h1[p2.x * H + f] * __int_as_float(p2.y)
                     + h1[p3.x * H + f] * __int_as_float(p3.y);
            }
            for (; e < deg; ++e) {
                int2 p = pp[e];
                acc += h1[p.x * H + f] * __int_as_float(p.y);
            }
            float gg = (acc + h1[i * H + f] * isd) * isd;
            gsh[w * 64 + f] = gg;
            __builtin_amdgcn_wave_barrier();
            float hv = b2[f];
            #pragma unroll 16
            for (int k = 0; k < 64; ++k) hv += gsh[w * 64 + k] * w2s[k * 64 + f];
            stc(&h2[i * H + f], hv);
            float dp = wred_f(hv * anorm[f]);
            float nn = wred_f(hv * hv);
            if (f == 0) stc(&score[i], dp / fmaxf(sqrtf(nn), 1e-8f));
            __builtin_amdgcn_wave_barrier();
        }
    }
    gsync(bar, 3);

    // ===== phase D: moments (blocks 0..191) =====
    if (b < MOM_BLKS) {
        float* Msh = (float*)smem;               // 16384
        float* Dsh = (float*)(smem + 16384);     // 256
        float accM[KTERMS], accD[KTERMS];
        #pragma unroll
        for (int k = 0; k < KTERMS; ++k) { accM[k] = 0.f; accD[k] = 0.f; }
        for (int j = b * 4 + w; j < N_NODES; j += MOM_BLKS * 4) {
            float sj = score[j];
            float wj = expf(-sj * sj);
            float hv = h2[j * H + f];
            float tm = wj * hv, td = wj;
            #pragma unroll
            for (int k = 0; k < KTERMS; ++k) {
                accM[k] += tm; tm *= sj;
                accD[k] += td; td *= sj;
            }
        }
        #pragma unroll
        for (int k = 0; k < KTERMS; ++k) Msh[(w * KTERMS + k) * 64 + f] = accM[k];
        if (f == 0) {
            #pragma unroll
            for (int k = 0; k < KTERMS; ++k) Dsh[w * KTERMS + k] = accD[k];
        }
        __syncthreads();
        for (int idx = t; idx < KTERMS * 64; idx += 256) {
            int k = idx >> 6, ff = idx & 63;
            float sum = Msh[(0 * KTERMS + k) * 64 + ff] + Msh[(1 * KTERMS + k) * 64 + ff]
                      + Msh[(2 * KTERMS + k) * 64 + ff] + Msh[(3 * KTERMS + k) * 64 + ff];
            unsafeAtomicAdd(&M[idx], (double)sum);
        }
        if (t < KTERMS) {
            float sum = Dsh[t] + Dsh[KTERMS + t] + Dsh[2 * KTERMS + t] + Dsh[3 * KTERMS + t];
            unsafeAtomicAdd(&m0[t], (double)sum);
        }
    }
    gsync(bar, 4);

    // ===== phase E: z + concat classifier, grid-stride groups of 16 =====
    {
        float* Ms  = (float*)smem;               // 4096
        float* m0s = (float*)(smem + 4096);      // 64
        float* cw  = (float*)(smem + 4160);      // 3584
        float* cb  = (float*)(smem + 7744);      // 32
        float* zh  = (float*)(smem + 7776);      // 2048
        for (int idx = t; idx < KTERMS * 64; idx += 256) Ms[idx] = (float)M[idx];
        if (t < KTERMS) m0s[t] = (float)m0[t];
        for (int idx = t; idx < 128 * C_CLS; idx += 256) cw[idx] = clfW[idx];
        if (t < C_CLS) cb[t] = clfb[t];
        __syncthreads();
        for (int g = b; g < 750; g += NBLK) {
            const int base = g * 16;
            for (int q = 0; q < 4; ++q) {
                int i = base + q * 4 + w;
                float s = score[i];
                float c = expf(-s * s);
                float t2 = 2.f * s;
                float num = 0.f, den = 0.f;
                #pragma unroll
                for (int k = 0; k < KTERMS; ++k) {
                    num += c * Ms[k * 64 + f];
                    den += c * m0s[k];
                    c *= t2 * (1.0f / (float)(k + 1));
                }
                zh[w * 128 + f] = h2[i * H + f];
                zh[w * 128 + 64 + f] = num / den;
                __builtin_amdgcn_wave_barrier();
                if (f < C_CLS) {
                    float o = cb[f];
                    #pragma unroll 8
                    for (int u = 0; u < 128; ++u) o += zh[w * 128 + u] * cw[u * C_CLS + f];
                    out[(size_t)i * C_CLS + f] = o;
                }
                __builtin_amdgcn_wave_barrier();
            }
        }
    }
}

// ---------------- launch
extern "C" void kernel_launch(void* const* d_in, const int* in_sizes, int n_in,
                              void* d_out, int out_size, void* d_ws, size_t ws_size,
                              hipStream_t stream) {
    (void)in_sizes; (void)n_in; (void)out_size; (void)ws_size;
    const float* x    = (const float*)d_in[0];
    const float* W1   = (const float*)d_in[1];
    const float* b1   = (const float*)d_in[2];
    const float* W2   = (const float*)d_in[3];
    const float* b2   = (const float*)d_in[4];
    const float* aux  = (const float*)d_in[5];
    const float* clfW = (const float*)d_in[6];
    const float* clfb = (const float*)d_in[7];
    const int*   ei   = (const int*)d_in[8];
    float* out = (float*)d_out;
    char* ws = (char*)d_ws;

    float*  hbuf  = (float*)(ws + 0);            // 3,072,000
    float*  h1    = (float*)(ws + 3072000);      // 3,072,000
    float*  h2    = (float*)(ws + 6144000);      // 3,072,000
    float*  score = (float*)(ws + 9216000);      // 48,000
    int*    csrc  = (int*)  (ws + 9264000);      // 4,608,000
    int*    cur   = (int*)  (ws + 13872000);     // 1,536,000 (padded lines)
    double* M     = (double*)(ws + 15408000);    // 8,192
    double* m0    = (double*)(ws + 15416192);    // 128
    int*    bar   = (int*)  (ws + 15416320);     // 3,072

    init_k<<<47, 256, 0, stream>>>(cur, M, m0, bar);
    mega_k<<<NBLK, 256, 0, stream>>>(x, W1, b1, W2, b2, aux, clfW, clfb, ei,
                                     hbuf, h1, h2, score, csrc, cur, M, m0, bar, out);
}

// Round 15
// 94.923 us; speedup vs baseline: 1.5712x; 1.5712x over previous
//
#include <hip/hip_runtime.h>
#include <hip/hip_bf16.h>

#define N_NODES 12000
#define N_EDGES 384000
#define F_IN 512
#define H 64
#define C_CLS 7
#define KTERMS 16
#define PAD 96
#define CSTR 32      // cur stride (ints): one 128B line per node (fill contention-free)
#define MOM_BLKS 192
#define NB 4         // nodes per agg block (1 per wave)
#define GEMM_BLKS 375   // 375*32 = 12000 rows exactly
#define FILL_BLKS 256
#define XS_STR 68

__device__ __forceinline__ float wred_f(float x) {
    #pragma unroll
    for (int o = 32; o > 0; o >>= 1) x += __shfl_xor(x, o);
    return x;
}

// ---------------- k0: zero exactly what's read later
__global__ __launch_bounds__(256) void init_k(int* __restrict__ cur,
                                              double* __restrict__ M,
                                              double* __restrict__ m0) {
    int i = blockIdx.x * 256 + threadIdx.x;
    if (i < N_NODES) cur[i * CSTR] = 0;
    if (i < KTERMS * 64) M[i] = 0.0;
    if (i < KTERMS) m0[i] = 0.0;
}

// ---------------- k1: gemm1 (blocks 0..374, 32-row tiles, 2x4 reg tiles) || CSR fill
__global__ __launch_bounds__(256) void k1_gemm_fill(const float* __restrict__ x,
                                                    const float* __restrict__ W1,
                                                    const int* __restrict__ ei,
                                                    float* __restrict__ hbuf,
                                                    int* __restrict__ cur,
                                                    int* __restrict__ csrc) {
    const int b = blockIdx.x, t = threadIdx.x;
    if (b < GEMM_BLKS) {
        __shared__ float xs[32 * XS_STR];   // [row][kk] row-major, 8704 B
        __shared__ float wsm[64 * 64];      // [kk][col], 16384 B
        const int tx = t & 15, ty = t >> 4; // tx: col group (4 cols), ty: row pair
        const int i0 = b * 32;
        float acc[2][4] = {};
        for (int k0 = 0; k0 < F_IN; k0 += 64) {
            #pragma unroll
            for (int q = 0; q < 2; ++q) {   // x slab 32x64, row-major float4
                int idx = t + q * 256;
                int row = idx >> 4, kg = idx & 15;
                *(float4*)(&xs[row * XS_STR + kg * 4]) =
                    *(const float4*)(x + (size_t)(i0 + row) * F_IN + k0 + kg * 4);
            }
            #pragma unroll
            for (int q = 0; q < 4; ++q) {   // W1 slab 64x64
                int idx = t + q * 256;
                int r = idx >> 4, cg = idx & 15;
                *(float4*)(&wsm[r * 64 + cg * 4]) =
                    *(const float4*)(W1 + (size_t)(k0 + r) * H + cg * 4);
            }
            __syncthreads();
            #pragma unroll
            for (int kk0 = 0; kk0 < 64; kk0 += 4) {
                float4 a0 = *(const float4*)(&xs[(ty * 2 + 0) * XS_STR + kk0]);
                float4 a1 = *(const float4*)(&xs[(ty * 2 + 1) * XS_STR + kk0]);
                float4 b0 = *(const float4*)(&wsm[(kk0 + 0) * 64 + tx * 4]);
                float4 b1v = *(const float4*)(&wsm[(kk0 + 1) * 64 + tx * 4]);
                float4 b2v = *(const float4*)(&wsm[(kk0 + 2) * 64 + tx * 4]);
                float4 b3v = *(const float4*)(&wsm[(kk0 + 3) * 64 + tx * 4]);
                acc[0][0] += a0.x * b0.x;  acc[0][1] += a0.x * b0.y;  acc[0][2] += a0.x * b0.z;  acc[0][3] += a0.x * b0.w;
                acc[0][0] += a0.y * b1v.x; acc[0][1] += a0.y * b1v.y; acc[0][2] += a0.y * b1v.z; acc[0][3] += a0.y * b1v.w;
                acc[0][0] += a0.z * b2v.x; acc[0][1] += a0.z * b2v.y; acc[0][2] += a0.z * b2v.z; acc[0][3] += a0.z * b2v.w;
                acc[0][0] += a0.w * b3v.x; acc[0][1] += a0.w * b3v.y; acc[0][2] += a0.w * b3v.z; acc[0][3] += a0.w * b3v.w;
                acc[1][0] += a1.x * b0.x;  acc[1][1] += a1.x * b0.y;  acc[1][2] += a1.x * b0.z;  acc[1][3] += a1.x * b0.w;
                acc[1][0] += a1.y * b1v.x; acc[1][1] += a1.y * b1v.y; acc[1][2] += a1.y * b1v.z; acc[1][3] += a1.y * b1v.w;
                acc[1][0] += a1.z * b2v.x; acc[1][1] += a1.z * b2v.y; acc[1][2] += a1.z * b2v.z; acc[1][3] += a1.z * b2v.w;
                acc[1][0] += a1.w * b3v.x; acc[1][1] += a1.w * b3v.y; acc[1][2] += a1.w * b3v.z; acc[1][3] += a1.w * b3v.w;
            }
            __syncthreads();
        }
        #pragma unroll
        for (int r = 0; r < 2; ++r) {
            int row = i0 + ty * 2 + r;
            *(float4*)(hbuf + (size_t)row * H + tx * 4) =
                make_float4(acc[r][0], acc[r][1], acc[r][2], acc[r][3]);
        }
    } else {
        for (int e = (b - GEMM_BLKS) * 256 + t; e < N_EDGES; e += FILL_BLKS * 256) {
            int s = ei[e];
            int d = ei[N_EDGES + e];
            int pos = atomicAdd(&cur[d * CSTR], 1);
            if (pos < PAD) csrc[d * PAD + pos] = s;   // overflow guard
        }
    }
}

// ---------------- k2: compact invs table (L1-resident for agg weight gathers)
__global__ __launch_bounds__(256) void invs_k(const int* __restrict__ cur,
                                              float* __restrict__ invs) {
    int i = blockIdx.x * 256 + threadIdx.x;
    if (i < N_NODES) invs[i] = rsqrtf((float)cur[i * CSTR] + 1.0f);
}

// ---------------- k3: agg1 = relu((Â @ hbuf) + b1)
__global__ __launch_bounds__(256) void agg1_k(const float* __restrict__ hbuf,
                                              const float* __restrict__ b1,
                                              const int* __restrict__ cur,
                                              const int* __restrict__ csrc,
                                              const float* __restrict__ invs,
                                              float* __restrict__ h1) {
    __shared__ int2 sPair[NB * PAD];
    __shared__ int sDeg[NB];
    __shared__ float sIsd[NB];
    const int t = threadIdx.x, f = t & 63, w = t >> 6;
    const int base = blockIdx.x * NB;
    if (t < NB) {
        sDeg[t] = min(cur[(base + t) * CSTR], PAD);
        sIsd[t] = invs[base + t];
    }
    __syncthreads();
    for (int idx = t; idx < NB * PAD; idx += 256) {
        int n = idx / PAD, e = idx - n * PAD;
        if (e < sDeg[n]) {
            int s = csrc[(base + n) * PAD + e];
            sPair[idx] = make_int2(s, __float_as_int(invs[s]));
        }
    }
    __syncthreads();
    const int i = base + w;
    const int deg = sDeg[w];
    const float isd = sIsd[w];
    const int2* pp = sPair + w * PAD;
    float acc = 0.f;
    int e = 0;
    for (; e + 8 <= deg; e += 8) {
        int2 p0 = pp[e], p1 = pp[e+1], p2 = pp[e+2], p3 = pp[e+3];
        int2 p4 = pp[e+4], p5 = pp[e+5], p6 = pp[e+6], p7 = pp[e+7];
        acc += hbuf[p0.x * H + f] * __int_as_float(p0.y)
             + hbuf[p1.x * H + f] * __int_as_float(p1.y)
             + hbuf[p2.x * H + f] * __int_as_float(p2.y)
             + hbuf[p3.x * H + f] * __int_as_float(p3.y)
             + hbuf[p4.x * H + f] * __int_as_float(p4.y)
             + hbuf[p5.x * H + f] * __int_as_float(p5.y)
             + hbuf[p6.x * H + f] * __int_as_float(p6.y)
             + hbuf[p7.x * H + f] * __int_as_float(p7.y);
    }
    for (; e + 4 <= deg; e += 4) {
        int2 p0 = pp[e], p1 = pp[e+1], p2 = pp[e+2], p3 = pp[e+3];
        acc += hbuf[p0.x * H + f] * __int_as_float(p0.y)
             + hbuf[p1.x * H + f] * __int_as_float(p1.y)
             + hbuf[p2.x * H + f] * __int_as_float(p2.y)
             + hbuf[p3.x * H + f] * __int_as_float(p3.y);
    }
    for (; e < deg; ++e) {
        int2 p = pp[e];
        acc += hbuf[p.x * H + f] * __int_as_float(p.y);
    }
    float res = (acc + hbuf[i * H + f] * isd) * isd + b1[f];
    h1[i * H + f] = fmaxf(res, 0.f);
}

// ---------------- k4: agg2 = (Â @ h1) @ W2 + b2, + cosine score
__global__ __launch_bounds__(256) void agg2_k(const float* __restrict__ h1,
                                              const float* __restrict__ W2,
                                              const float* __restrict__ b2,
                                              const float* __restrict__ aux,
                                              const int* __restrict__ cur,
                                              const int* __restrict__ csrc,
                                              const float* __restrict__ invs,
                                              float* __restrict__ h2,
                                              float* __restrict__ score) {
    __shared__ float w2s[64 * 64];
    __shared__ int2 sPair[NB * PAD];
    __shared__ int sDeg[NB];
    __shared__ float sIsd[NB];
    __shared__ float anorm[64];
    __shared__ float gsh[NB * 64];
    const int t = threadIdx.x, f = t & 63, w = t >> 6;
    const int base = blockIdx.x * NB;
    #pragma unroll
    for (int q = 0; q < 4; ++q) {
        int idx = t + q * 256;
        int r = idx >> 4, c4 = idx & 15;
        *(float4*)(&w2s[r * 64 + c4 * 4]) = *(const float4*)(W2 + r * H + c4 * 4);
    }
    if (t < NB) {
        sDeg[t] = min(cur[(base + t) * CSTR], PAD);
        sIsd[t] = invs[base + t];
    }
    if (t < 64) {
        float av = aux[t];
        anorm[t] = av * rsqrtf(fmaxf(wred_f(av * av), 1e-24f));
    }
    __syncthreads();
    for (int idx = t; idx < NB * PAD; idx += 256) {
        int n = idx / PAD, e = idx - n * PAD;
        if (e < sDeg[n]) {
            int s = csrc[(base + n) * PAD + e];
            sPair[idx] = make_int2(s, __float_as_int(invs[s]));
        }
    }
    __syncthreads();
    const int i = base + w;
    const int deg = sDeg[w];
    const float isd = sIsd[w];
    const int2* pp = sPair + w * PAD;
    float acc = 0.f;
    int e = 0;
    for (; e + 8 <= deg; e += 8) {
        int2 p0 = pp[e], p1 = pp[e+1], p2 = pp[e+2], p3 = pp[e+3];
        int2 p4 = pp[e+4], p5 = pp[e+5], p6 = pp[e+6], p7 = pp[e+7];
        acc += h1[p0.x * H + f] * __int_as_float(p0.y)
             + h1[p1.x * H + f] * __int_as_float(p1.y)
             + h1[p2.x * H + f] * __int_as_float(p2.y)
             + h1[p3.x * H + f] * __int_as_float(p3.y)
             + h1[p4.x * H + f] * __int_as_float(p4.y)
             + h1[p5.x * H + f] * __int_as_float(p5.y)
             + h1[p6.x * H + f] * __int_as_float(p6.y)
             + h1[p7.x * H + f] * __int_as_float(p7.y);
    }
    for (; e + 4 <= deg; e += 4) {
        int2 p0 = pp[e], p1 = pp[e+1], p2 = pp[e+2], p3 = pp[e+3];
        acc += h1[p0.x * H + f] * __int_as_float(p0.y)
             + h1[p1.x * H + f] * __int_as_float(p1.y)
             + h1[p2.x * H + f] * __int_as_float(p2.y)
             + h1[p3.x * H + f] * __int_as_float(p3.y);
    }
    for (; e < deg; ++e) {
        int2 p = pp[e];
        acc += h1[p.x * H + f] * __int_as_float(p.y);
    }
    float g = (acc + h1[i * H + f] * isd) * isd;
    gsh[w * 64 + f] = g;
    __builtin_amdgcn_wave_barrier();
    float hv = b2[f];
    #pragma unroll 16
    for (int k = 0; k < 64; ++k) hv += gsh[w * 64 + k] * w2s[k * 64 + f];
    h2[i * H + f] = hv;
    float dp = wred_f(hv * anorm[f]);
    float nn = wred_f(hv * hv);
    if (f == 0) score[i] = dp / fmaxf(sqrtf(nn), 1e-8f);
}

// ---------------- k5: moments M[k][f] = sum_j w_j s_j^k h2[j][f]; m0[k] likewise
__global__ __launch_bounds__(256) void momden_k(const float* __restrict__ h2,
                                                const float* __restrict__ score,
                                                double* __restrict__ M,
                                                double* __restrict__ m0) {
    const int t = threadIdx.x, f = t & 63, g = t >> 6;
    float accM[KTERMS], accD[KTERMS];
    #pragma unroll
    for (int k = 0; k < KTERMS; ++k) { accM[k] = 0.f; accD[k] = 0.f; }
    for (int j = blockIdx.x * 4 + g; j < N_NODES; j += MOM_BLKS * 4) {
        float sj = score[j];
        float wj = expf(-sj * sj);
        float hv = h2[j * H + f];
        float tm = wj * hv, td = wj;
        #pragma unroll
        for (int k = 0; k < KTERMS; ++k) {
            accM[k] += tm; tm *= sj;
            accD[k] += td; td *= sj;
        }
    }
    __shared__ float Msh[4 * KTERMS * 64];
    __shared__ float Dsh[4 * KTERMS];
    #pragma unroll
    for (int k = 0; k < KTERMS; ++k) Msh[(g * KTERMS + k) * 64 + f] = accM[k];
    if (f == 0) {
        #pragma unroll
        for (int k = 0; k < KTERMS; ++k) Dsh[g * KTERMS + k] = accD[k];
    }
    __syncthreads();
    for (int idx = t; idx < KTERMS * 64; idx += 256) {
        int k = idx >> 6, ff = idx & 63;
        float sum = Msh[(0 * KTERMS + k) * 64 + ff] + Msh[(1 * KTERMS + k) * 64 + ff]
                  + Msh[(2 * KTERMS + k) * 64 + ff] + Msh[(3 * KTERMS + k) * 64 + ff];
        unsafeAtomicAdd(&M[idx], (double)sum);
    }
    if (t < KTERMS) {
        float sum = Dsh[t] + Dsh[KTERMS + t] + Dsh[2 * KTERMS + t] + Dsh[3 * KTERMS + t];
        unsafeAtomicAdd(&m0[t], (double)sum);
    }
}

// ---------------- k6: z + concat classifier
__global__ __launch_bounds__(256) void final_k(const float* __restrict__ h2,
                                               const float* __restrict__ score,
                                               const double* __restrict__ M,
                                               const double* __restrict__ m0,
                                               const float* __restrict__ clfW,
                                               const float* __restrict__ clfb,
                                               float* __restrict__ out) {
    __shared__ float Ms[KTERMS * 64];
    __shared__ float m0s[KTERMS];
    __shared__ float cw[128 * C_CLS];
    __shared__ float cb[8];
    __shared__ float zh[4 * 128];
    const int t = threadIdx.x, f = t & 63, w = t >> 6;
    for (int idx = t; idx < KTERMS * 64; idx += 256) Ms[idx] = (float)M[idx];
    if (t < KTERMS) m0s[t] = (float)m0[t];
    for (int idx = t; idx < 128 * C_CLS; idx += 256) cw[idx] = clfW[idx];
    if (t < C_CLS) cb[t] = clfb[t];
    __syncthreads();
    const int base = blockIdx.x * 16;
    for (int q = 0; q < 4; ++q) {
        int i = base + q * 4 + w;
        float s = score[i];
        float c = expf(-s * s);
        float t2 = 2.f * s;
        float num = 0.f, den = 0.f;
        #pragma unroll
        for (int k = 0; k < KTERMS; ++k) {
            num += c * Ms[k * 64 + f];
            den += c * m0s[k];
            c *= t2 * (1.0f / (float)(k + 1));
        }
        zh[w * 128 + f] = h2[i * H + f];
        zh[w * 128 + 64 + f] = num / den;
        __builtin_amdgcn_wave_barrier();
        if (f < C_CLS) {
            float o = cb[f];
            #pragma unroll 8
            for (int u = 0; u < 128; ++u) o += zh[w * 128 + u] * cw[u * C_CLS + f];
            out[(size_t)i * C_CLS + f] = o;
        }
        __builtin_amdgcn_wave_barrier();
    }
}

// ---------------- launch
extern "C" void kernel_launch(void* const* d_in, const int* in_sizes, int n_in,
                              void* d_out, int out_size, void* d_ws, size_t ws_size,
                              hipStream_t stream) {
    (void)in_sizes; (void)n_in; (void)out_size; (void)ws_size;
    const float* x    = (const float*)d_in[0];
    const float* W1   = (const float*)d_in[1];
    const float* b1   = (const float*)d_in[2];
    const float* W2   = (const float*)d_in[3];
    const float* b2   = (const float*)d_in[4];
    const float* aux  = (const float*)d_in[5];
    const float* clfW = (const float*)d_in[6];
    const float* clfb = (const float*)d_in[7];
    const int*   ei   = (const int*)d_in[8];
    float* out = (float*)d_out;
    char* ws = (char*)d_ws;

    float*  hbuf  = (float*)(ws + 0);            // 3,072,000
    float*  h1    = (float*)(ws + 3072000);      // 3,072,000
    float*  h2    = (float*)(ws + 6144000);      // 3,072,000
    float*  score = (float*)(ws + 9216000);      // 48,000
    float*  invs  = (float*)(ws + 9264000);      // 48,000
    int*    csrc  = (int*)  (ws + 9312000);      // 4,608,000
    int*    cur   = (int*)  (ws + 13920000);     // 1,536,000 (padded lines)
    double* M     = (double*)(ws + 15456000);    // 8,192
    double* m0    = (double*)(ws + 15464192);    // 128

    init_k<<<47, 256, 0, stream>>>(cur, M, m0);
    k1_gemm_fill<<<GEMM_BLKS + FILL_BLKS, 256, 0, stream>>>(x, W1, ei, hbuf, cur, csrc);
    invs_k<<<47, 256, 0, stream>>>(cur, invs);
    agg1_k<<<N_NODES / NB, 256, 0, stream>>>(hbuf, b1, cur, csrc, invs, h1);
    agg2_k<<<N_NODES / NB, 256, 0, stream>>>(h1, W2, b2, aux, cur, csrc, invs, h2, score);
    momden_k<<<MOM_BLKS, 256, 0, stream>>>(h2, score, M, m0);
    final_k<<<750, 256, 0, stream>>>(h2, score, M, m0, clfW, clfb, out);
}